// Round 4
// baseline (401.636 us; speedup 1.0000x reference)
//
#include <hip/hip_runtime.h>

#define IN_DIM 128
#define HID 64
#define G1CAP 6144          // LDS floats for k_gather1 staging (E[block]=4096, +32 sigma)

// ---- bf16 helpers (RNE) ----
static __device__ __forceinline__ unsigned short f2bf(float f) {
    unsigned u = __float_as_uint(f);
    u += 0x7FFF + ((u >> 16) & 1);
    return (unsigned short)(u >> 16);
}

typedef short bf16x8 __attribute__((ext_vector_type(8)));
typedef float f32x4 __attribute__((ext_vector_type(4)));

// =================== CSR build: direct global-atomic version ===================
// k_zero -> k_deg (atomic in-degree) -> scanA/B/C (rowStart, dis, cur) -> k_place

__global__ __launch_bounds__(256) void k_zero(int* __restrict__ deg, int N) {
    int i = blockIdx.x * 256 + threadIdx.x;
    if (i < N) deg[i] = 0;
}

__global__ __launch_bounds__(256) void k_deg(const int* __restrict__ dst,
                                             int* __restrict__ deg, int E) {
    int e = (blockIdx.x * 256 + threadIdx.x) * 4;
    if (e + 4 <= E) {
        int4 d = *(const int4*)(dst + e);
        atomicAdd(&deg[d.x], 1);
        atomicAdd(&deg[d.y], 1);
        atomicAdd(&deg[d.z], 1);
        atomicAdd(&deg[d.w], 1);
    } else {
        for (; e < E; ++e) atomicAdd(&deg[dst[e]], 1);
    }
}

// block-local exclusive scan of deg -> rowStart (local part) + per-block totals
__global__ __launch_bounds__(256) void k_scanA(const int* __restrict__ deg,
                                               int* __restrict__ rowStart,
                                               int* __restrict__ blkSum, int N) {
    __shared__ int tmp[256];
    int i = blockIdx.x * 256 + threadIdx.x;
    int t = threadIdx.x;
    int v = (i < N) ? deg[i] : 0;
    tmp[t] = v;
    __syncthreads();
    for (int off = 1; off < 256; off <<= 1) {
        int a = (t >= off) ? tmp[t - off] : 0;
        __syncthreads();
        tmp[t] += a;
        __syncthreads();
    }
    if (i < N) rowStart[i] = tmp[t] - v;   // local exclusive
    if (t == 255) blkSum[blockIdx.x] = tmp[255];
}

// single-block scan over per-block totals -> blkBase; also rowStart[N] = E
__global__ __launch_bounds__(512) void k_scanB(const int* __restrict__ blkSum,
                                               int* __restrict__ blkBase,
                                               int NB, int* __restrict__ rowStart,
                                               int N, int E) {
    __shared__ int tmp[512];
    int t = threadIdx.x;
    int v = (t < NB) ? blkSum[t] : 0;
    tmp[t] = v;
    __syncthreads();
    for (int off = 1; off < 512; off <<= 1) {
        int a = (t >= off) ? tmp[t - off] : 0;
        __syncthreads();
        tmp[t] += a;
        __syncthreads();
    }
    if (t < NB) blkBase[t] = tmp[t] - v;
    if (t == 0) rowStart[N] = E;
}

// finalize rowStart, seed cur[] counters, compute dis
__global__ __launch_bounds__(256) void k_scanC(const int* __restrict__ blkBase,
                                               const int* __restrict__ deg,
                                               int* __restrict__ rowStart,
                                               int* __restrict__ cur,
                                               float* __restrict__ dis, int N) {
    int i = blockIdx.x * 256 + threadIdx.x;
    if (i < N) {
        int r = rowStart[i] + blkBase[blockIdx.x];
        rowStart[i] = r;
        cur[i] = r;
        dis[i] = rsqrtf((float)deg[i] + 1.0f);
    }
}

// placement: esrc[pos] = src*128 (byte offset of bf16 row), pos via atomic on cur
__global__ __launch_bounds__(256) void k_place(const int* __restrict__ src,
                                               const int* __restrict__ dst,
                                               int* __restrict__ cur,
                                               int* __restrict__ esrc, int E) {
    int e = (blockIdx.x * 256 + threadIdx.x) * 4;
    if (e + 4 <= E) {
        int4 s = *(const int4*)(src + e);
        int4 d = *(const int4*)(dst + e);
        int p0 = atomicAdd(&cur[d.x], 1); esrc[p0] = s.x << 7;
        int p1 = atomicAdd(&cur[d.y], 1); esrc[p1] = s.y << 7;
        int p2 = atomicAdd(&cur[d.z], 1); esrc[p2] = s.z << 7;
        int p3 = atomicAdd(&cur[d.w], 1); esrc[p3] = s.w << 7;
    } else {
        for (; e < E; ++e) {
            int p = atomicAdd(&cur[dst[e]], 1);
            esrc[p] = src[e] << 7;
        }
    }
}

// ------- MFMA transform: Hbs[N,64] = bf16( (X[N,K] @ W[K,64]) * dis[row] ) -------
template <int K, typename T>
__global__ __launch_bounds__(256) void k_mmx(const T* __restrict__ X,
                                             const float* __restrict__ W,
                                             const float* __restrict__ dis,
                                             unsigned short* __restrict__ Hbs, int N) {
    constexpr int WP = K + 8;
    __shared__ unsigned short Wt[64 * WP];
    const int tid = threadIdx.x;
    for (int i = tid; i < K * 64; i += 256) {
        int k = i >> 6, n = i & 63;
        Wt[n * WP + k] = f2bf(W[i]);
    }
    __syncthreads();
    const int lane = tid & 63;
    const int m16 = lane & 15;
    const int quad = lane >> 4;
    const int rowBase = blockIdx.x * 64 + (tid >> 6) * 16;
    const int rowc = min(rowBase + m16, N - 1);

    f32x4 acc0 = {0.f, 0.f, 0.f, 0.f};
    f32x4 acc1 = acc0, acc2 = acc0, acc3 = acc0;
    const T* xrow = X + (size_t)rowc * K;
#pragma unroll
    for (int k0 = 0; k0 < K; k0 += 32) {
        bf16x8 af;
        if constexpr (sizeof(T) == 4) {
            const float* xp = (const float*)xrow + k0 + quad * 8;
            float4 xa = *(const float4*)xp;
            float4 xb = *(const float4*)(xp + 4);
            af[0] = (short)f2bf(xa.x); af[1] = (short)f2bf(xa.y);
            af[2] = (short)f2bf(xa.z); af[3] = (short)f2bf(xa.w);
            af[4] = (short)f2bf(xb.x); af[5] = (short)f2bf(xb.y);
            af[6] = (short)f2bf(xb.z); af[7] = (short)f2bf(xb.w);
        } else {
            af = *(const bf16x8*)((const unsigned short*)xrow + k0 + quad * 8);
        }
        const unsigned short* wp = &Wt[m16 * WP + k0 + quad * 8];
        bf16x8 b0 = *(const bf16x8*)(wp);
        bf16x8 b1 = *(const bf16x8*)(wp + 16 * WP);
        bf16x8 b2 = *(const bf16x8*)(wp + 32 * WP);
        bf16x8 b3 = *(const bf16x8*)(wp + 48 * WP);
        acc0 = __builtin_amdgcn_mfma_f32_16x16x32_bf16(af, b0, acc0, 0, 0, 0);
        acc1 = __builtin_amdgcn_mfma_f32_16x16x32_bf16(af, b1, acc1, 0, 0, 0);
        acc2 = __builtin_amdgcn_mfma_f32_16x16x32_bf16(af, b2, acc2, 0, 0, 0);
        acc3 = __builtin_amdgcn_mfma_f32_16x16x32_bf16(af, b3, acc3, 0, 0, 0);
    }
#pragma unroll
    for (int reg = 0; reg < 4; ++reg) {
        int r = rowBase + quad * 4 + reg;
        if (r < N) {
            float dsc = dis[r];
            unsigned short* hp = Hbs + (size_t)r * 64 + m16;
            hp[0]  = f2bf(acc0[reg] * dsc);
            hp[16] = f2bf(acc1[reg] * dsc);
            hp[32] = f2bf(acc2[reg] * dsc);
            hp[48] = f2bf(acc3[reg] * dsc);
        }
    }
}

// ------- gather-aggregate: quarter-wave (16 lanes) per node, dwordx2/lane -----
// Each quarter OWNS its node's edge-offset batches (shfl sources stay inside the
// quarter; quarter-uniform loop bounds -> all 16 lanes of an active quarter are
// active -> bpermute always reads active lanes). Full 16-edge batches issue a
// 16-deep independent-load cascade (128B/lane in flight); tails use 8/4/masked.
// MODE 1: out = relu row, stored bf16 (feeds bf16 mmx)
// MODE 2: relu row, dot with W3, write colS[i] = dot*dis and out[i] = dot*dis^2 + b3

#define BLO(d) __uint_as_float((d) << 16)
#define BHI(d) __uint_as_float((d) & 0xFFFF0000u)
#define ACC2(A, Q) { A.x += BLO((Q).x); A.y += BHI((Q).x);                     \
                     A.z += BLO((Q).y); A.w += BHI((Q).y); }

template <int MODE>
__global__ __launch_bounds__(256) void k_gather64(const unsigned short* __restrict__ Hbs,
                                                  const int* __restrict__ esrc,
                                                  const int* __restrict__ rowStart,
                                                  const float* __restrict__ dis,
                                                  const float* __restrict__ b,
                                                  unsigned short* __restrict__ outB,
                                                  const float* __restrict__ W3,
                                                  const float* __restrict__ b3,
                                                  float* __restrict__ colS,
                                                  float* __restrict__ outF,
                                                  int N) {
    int lane = threadIdx.x & 63;
    int c = lane & 15;          // 8B chunk of the 128B row
    int sub = lane >> 4;        // quarter index == node slot
    int qb = sub << 4;          // quarter's first lane (shfl base)
    int wave = (blockIdx.x * 256 + threadIdx.x) >> 6;
    int g0 = wave * 4;
    if (g0 >= N) return;
    const char* hb = (const char*)Hbs + c * 8;

    int rb = rowStart[min(g0 + lane, N)];      // wave fully active here
    int Rq  = __shfl(rb, sub, 64);             // this quarter's segment [Rq, Rq1)
    int Rq1 = __shfl(rb, sub + 1, 64);
    int n = g0 + sub;                          // this quarter's node
    int nc = min(n, N - 1);

    // self-loop seed: quarter's own row (h[n]*dis[n]); scaled by dis[n] later
    float4 a;
    {
        uint2 sd = *(const uint2*)(hb + ((size_t)nc << 7));
        a.x = BLO(sd.x); a.y = BHI(sd.x); a.z = BLO(sd.y); a.w = BHI(sd.y);
    }

    unsigned eoff = (Rq + c < Rq1) ? (unsigned)esrc[Rq + c] : 0u;
    for (int bb = Rq; bb < Rq1; bb += 16) {
        int cnt = min(16, Rq1 - bb);
        // prefetch next batch's offsets (independent of this batch's work)
        unsigned eoffN = (bb + 16 + c < Rq1) ? (unsigned)esrc[bb + 16 + c] : 0u;

        int j = 0;
        if (cnt == 16) {   // full batch: one 16-deep cascade
            unsigned o0 = __shfl(eoff, qb + 0, 64);
            unsigned o1 = __shfl(eoff, qb + 1, 64);
            unsigned o2 = __shfl(eoff, qb + 2, 64);
            unsigned o3 = __shfl(eoff, qb + 3, 64);
            unsigned o4 = __shfl(eoff, qb + 4, 64);
            unsigned o5 = __shfl(eoff, qb + 5, 64);
            unsigned o6 = __shfl(eoff, qb + 6, 64);
            unsigned o7 = __shfl(eoff, qb + 7, 64);
            unsigned o8 = __shfl(eoff, qb + 8, 64);
            unsigned o9 = __shfl(eoff, qb + 9, 64);
            unsigned oA = __shfl(eoff, qb + 10, 64);
            unsigned oB = __shfl(eoff, qb + 11, 64);
            unsigned oC = __shfl(eoff, qb + 12, 64);
            unsigned oD = __shfl(eoff, qb + 13, 64);
            unsigned oE = __shfl(eoff, qb + 14, 64);
            unsigned oF = __shfl(eoff, qb + 15, 64);
            uint2 q0 = *(const uint2*)(hb + o0);
            uint2 q1 = *(const uint2*)(hb + o1);
            uint2 q2 = *(const uint2*)(hb + o2);
            uint2 q3 = *(const uint2*)(hb + o3);
            uint2 q4 = *(const uint2*)(hb + o4);
            uint2 q5 = *(const uint2*)(hb + o5);
            uint2 q6 = *(const uint2*)(hb + o6);
            uint2 q7 = *(const uint2*)(hb + o7);
            uint2 q8 = *(const uint2*)(hb + o8);
            uint2 q9 = *(const uint2*)(hb + o9);
            uint2 qA = *(const uint2*)(hb + oA);
            uint2 qB = *(const uint2*)(hb + oB);
            uint2 qC = *(const uint2*)(hb + oC);
            uint2 qD = *(const uint2*)(hb + oD);
            uint2 qE = *(const uint2*)(hb + oE);
            uint2 qF = *(const uint2*)(hb + oF);
            ACC2(a, q0) ACC2(a, q1) ACC2(a, q2) ACC2(a, q3)
            ACC2(a, q4) ACC2(a, q5) ACC2(a, q6) ACC2(a, q7)
            ACC2(a, q8) ACC2(a, q9) ACC2(a, qA) ACC2(a, qB)
            ACC2(a, qC) ACC2(a, qD) ACC2(a, qE) ACC2(a, qF)
            j = 16;
        } else {
            for (; j + 8 <= cnt; j += 8) {
                unsigned o0 = __shfl(eoff, qb + j + 0, 64);
                unsigned o1 = __shfl(eoff, qb + j + 1, 64);
                unsigned o2 = __shfl(eoff, qb + j + 2, 64);
                unsigned o3 = __shfl(eoff, qb + j + 3, 64);
                unsigned o4 = __shfl(eoff, qb + j + 4, 64);
                unsigned o5 = __shfl(eoff, qb + j + 5, 64);
                unsigned o6 = __shfl(eoff, qb + j + 6, 64);
                unsigned o7 = __shfl(eoff, qb + j + 7, 64);
                uint2 q0 = *(const uint2*)(hb + o0);
                uint2 q1 = *(const uint2*)(hb + o1);
                uint2 q2 = *(const uint2*)(hb + o2);
                uint2 q3 = *(const uint2*)(hb + o3);
                uint2 q4 = *(const uint2*)(hb + o4);
                uint2 q5 = *(const uint2*)(hb + o5);
                uint2 q6 = *(const uint2*)(hb + o6);
                uint2 q7 = *(const uint2*)(hb + o7);
                ACC2(a, q0) ACC2(a, q1) ACC2(a, q2) ACC2(a, q3)
                ACC2(a, q4) ACC2(a, q5) ACC2(a, q6) ACC2(a, q7)
            }
            if (j + 4 <= cnt) {
                unsigned o0 = __shfl(eoff, qb + j + 0, 64);
                unsigned o1 = __shfl(eoff, qb + j + 1, 64);
                unsigned o2 = __shfl(eoff, qb + j + 2, 64);
                unsigned o3 = __shfl(eoff, qb + j + 3, 64);
                uint2 q0 = *(const uint2*)(hb + o0);
                uint2 q1 = *(const uint2*)(hb + o1);
                uint2 q2 = *(const uint2*)(hb + o2);
                uint2 q3 = *(const uint2*)(hb + o3);
                ACC2(a, q0) ACC2(a, q1) ACC2(a, q2) ACC2(a, q3)
                j += 4;
            }
            if (j < cnt) {   // masked remainder 1..3 (slot 0 always valid)
                bool v1 = j + 1 < cnt, v2 = j + 2 < cnt;
                unsigned o0 = __shfl(eoff, qb + j, 64);
                unsigned o1 = __shfl(eoff, v1 ? qb + j + 1 : qb + j, 64);
                unsigned o2 = __shfl(eoff, v2 ? qb + j + 2 : qb + j, 64);
                uint2 q0 = *(const uint2*)(hb + o0);
                uint2 q1 = *(const uint2*)(hb + o1);
                uint2 q2 = *(const uint2*)(hb + o2);
                if (!v1) { q1.x = 0u; q1.y = 0u; }
                if (!v2) { q2.x = 0u; q2.y = 0u; }
                ACC2(a, q0) ACC2(a, q1) ACC2(a, q2)
            }
        }
        eoff = eoffN;
    }

    // epilogue: each quarter finalizes its own node; no cross-sub reduction
    float ds = dis[nc];
    float4 bl = ((const float4*)b)[c];
    float4 v;
    v.x = fmaxf(a.x * ds + bl.x, 0.f);
    v.y = fmaxf(a.y * ds + bl.y, 0.f);
    v.z = fmaxf(a.z * ds + bl.z, 0.f);
    v.w = fmaxf(a.w * ds + bl.w, 0.f);

    if (MODE == 1) {
        uint2 pv;
        pv.x = (unsigned)f2bf(v.x) | ((unsigned)f2bf(v.y) << 16);
        pv.y = (unsigned)f2bf(v.z) | ((unsigned)f2bf(v.w) << 16);
        if (n < N) ((uint2*)outB)[(size_t)n * 16 + c] = pv;   // 512B/wave coalesced
    } else {
        float4 w3 = ((const float4*)W3)[c];
        float t = v.x * w3.x + v.y * w3.y + v.z * w3.z + v.w * w3.w;
        t += __shfl_xor(t, 1, 64);
        t += __shfl_xor(t, 2, 64);
        t += __shfl_xor(t, 4, 64);
        t += __shfl_xor(t, 8, 64);
        if (c == 0 && n < N) {
            colS[n] = t * ds;
            outF[n] = t * ds * ds + b3[0];
        }
    }
}

// layer-3 aggregation: stage block's colS values in LDS (parallel loads),
// then per-node serial sum out of LDS. out[i] += dis[i] * sum colS[esrc>>7]
__global__ __launch_bounds__(256) void k_gather1(const float* __restrict__ colS,
                                                 const int* __restrict__ esrc,
                                                 const int* __restrict__ rowStart,
                                                 const float* __restrict__ dis,
                                                 float* __restrict__ out, int N) {
    __shared__ float ls[G1CAP];
    int tid = threadIdx.x;
    int n0 = blockIdx.x * 256;
    int nEnd = min(n0 + 256, N);
    int r0 = rowStart[n0];
    int r1 = rowStart[nEnd];
    int cnt = r1 - r0;
    if (cnt <= G1CAP) {
        for (int i = tid; i < cnt; i += 256)
            ls[i] = colS[((unsigned)esrc[r0 + i]) >> 7];
        __syncthreads();
        int n = n0 + tid;
        if (n < N) {
            int a = rowStart[n] - r0, bnd = rowStart[n + 1] - r0;
            float acc = 0.0f;
            for (int e = a; e < bnd; ++e) acc += ls[e];
            out[n] += acc * dis[n];
        }
    } else {   // statistically unreachable fallback
        int n = n0 + tid;
        if (n < N) {
            int a = rowStart[n], bnd = rowStart[n + 1];
            float acc = 0.0f;
            for (int e = a; e < bnd; ++e) acc += colS[((unsigned)esrc[e]) >> 7];
            out[n] += acc * dis[n];
        }
    }
}

extern "C" void kernel_launch(void* const* d_in, const int* in_sizes, int n_in,
                              void* d_out, int out_size, void* d_ws, size_t ws_size,
                              hipStream_t stream) {
    const float* x  = (const float*)d_in[0];
    const int*   ei = (const int*)d_in[1];
    const float* W1 = (const float*)d_in[2];
    const float* b1 = (const float*)d_in[3];
    const float* W2 = (const float*)d_in[4];
    const float* b2 = (const float*)d_in[5];
    const float* W3 = (const float*)d_in[6];
    const float* b3 = (const float*)d_in[7];
    float* out = (float*)d_out;

    const int N = in_sizes[0] / IN_DIM;     // 100000
    const int E = in_sizes[1] / 2;          // 1600000
    const int* src = ei;
    const int* dst = ei + E;

    // ---- workspace layout ----
    char* w = (char*)d_ws;
    auto alloc = [&](size_t bytes) {
        char* p = w;
        w += (bytes + 1023) & ~(size_t)1023;
        return p;
    };
    float*          dis        = (float*)alloc((size_t)N * 4);
    unsigned short* Hbs        = (unsigned short*)alloc((size_t)N * 64 * 2);
    unsigned short* Hb1        = (unsigned short*)alloc((size_t)N * 64 * 2);
    float*          colS       = (float*)alloc((size_t)N * 4);
    int*            rowStart   = (int*)alloc((size_t)(N + 1) * 4);
    int*            deg        = (int*)alloc((size_t)N * 4);
    int*            cur        = (int*)alloc((size_t)N * 4);
    int*            blkSum     = (int*)alloc((size_t)512 * 4);
    int*            blkBase    = (int*)alloc((size_t)512 * 4);
    int*            esrc       = (int*)alloc((size_t)E * 4);

    const int NB_N  = (N + 255) / 256;                  // 391
    const int NB_E4 = ((E + 3) / 4 + 255) / 256;        // 1563
    const int NB_MX = (N + 63) / 64;                    // MFMA transform blocks
    const int NB_G4 = ((N + 3) / 4 * 64 + 255) / 256;   // 4 nodes per wave

    // ---- CSR build via global atomics (no tmp1 round-trip) ----
    k_zero <<<NB_N,  256, 0, stream>>>(deg, N);
    k_deg  <<<NB_E4, 256, 0, stream>>>(dst, deg, E);
    k_scanA<<<NB_N,  256, 0, stream>>>(deg, rowStart, blkSum, N);
    k_scanB<<<1,     512, 0, stream>>>(blkSum, blkBase, NB_N, rowStart, N, E);
    k_scanC<<<NB_N,  256, 0, stream>>>(blkBase, deg, rowStart, cur, dis, N);
    k_place<<<NB_E4, 256, 0, stream>>>(src, dst, cur, esrc, E);

    // ---- layer 1: mmx fp32->bf16, gather -> bf16 rows ----
    k_mmx<IN_DIM, float><<<NB_MX, 256, 0, stream>>>(x, W1, dis, Hbs, N);
    k_gather64<1><<<NB_G4, 256, 0, stream>>>(Hbs, esrc, rowStart, dis, b1,
                                             Hb1, nullptr, nullptr, nullptr, nullptr, N);

    // ---- layer 2: mmx bf16 input, gather fused with W3 dot ----
    k_mmx<HID, unsigned short><<<NB_MX, 256, 0, stream>>>(Hb1, W2, dis, Hbs, N);
    k_gather64<2><<<NB_G4, 256, 0, stream>>>(Hbs, esrc, rowStart, dis, b2,
                                             nullptr, W3, b3, colS, out, N);

    // ---- layer 3 aggregation ----
    k_gather1<<<NB_N, 256, 0, stream>>>(colS, esrc, rowStart, dis, out, N);
}

// Round 5
// 237.454 us; speedup vs baseline: 1.6914x; 1.6914x over previous
//
#include <hip/hip_runtime.h>

#define IN_DIM 128
#define HID 64
#define MAXC 400            // >= ceil(N/256); N=100000 -> 391 coarse buckets
#define MAXB 512            // >= NBLK = ceil(E/EPB) = 391
#define EPB 4096
#define DPT 512             // degplace threads per block
#define ELS_CAP 5120        // LDS staged esrc per bucket (mean 4096, sigma 64 -> +16 sigma)
#define G1CAP 6144          // LDS floats for k_gather1 staging (E[block]=4096, +32 sigma)

// ---- bf16 helpers (RNE) ----
static __device__ __forceinline__ unsigned short f2bf(float f) {
    unsigned u = __float_as_uint(f);
    u += 0x7FFF + ((u >> 16) & 1);
    return (unsigned short)(u >> 16);
}

typedef short bf16x8 __attribute__((ext_vector_type(8)));
typedef float f32x4 __attribute__((ext_vector_type(4)));

// ---- pass 0: per-block bucket histogram -> hmat[blk][cb] (coalesced row) ----
__global__ __launch_bounds__(256) void k_hist2(const int* __restrict__ dst,
                                               int* __restrict__ hmat, int E, int NC) {
    __shared__ int h[MAXC];
    int tid = threadIdx.x, blk = blockIdx.x;
    for (int i = tid; i < NC; i += 256) h[i] = 0;
    __syncthreads();
    int e0 = blk * EPB, e1 = min(e0 + EPB, E);
    for (int e = e0 + tid; e < e1; e += 256) atomicAdd(&h[dst[e] >> 8], 1);
    __syncthreads();
    for (int i = tid; i < NC; i += 256) hmat[blk * MAXC + i] = h[i];
}

// ---- per-bucket exclusive scan across blocks (in-place) + bucket totals ----
__global__ __launch_bounds__(512) void k_bktscan(int* __restrict__ hmat,
                                                 int* __restrict__ bktTotal,
                                                 int NBLK, int NC) {
    __shared__ int tmp[512];
    int cb = blockIdx.x;
    int t = threadIdx.x;
    int v = (t < NBLK) ? hmat[t * MAXC + cb] : 0;
    tmp[t] = v;
    __syncthreads();
    for (int off = 1; off < 512; off <<= 1) {
        int a = (t >= off) ? tmp[t - off] : 0;
        __syncthreads();
        tmp[t] += a;
        __syncthreads();
    }
    if (t < NBLK) hmat[t * MAXC + cb] = tmp[t] - v;   // exclusive prefix within bucket
    if (t == 511) bktTotal[cb] = tmp[511];
}

// ---- single-block scan over bucket totals -> coarseStart ----
__global__ __launch_bounds__(512) void k_cscan(const int* __restrict__ bktTotal,
                                               int* __restrict__ coarseStart,
                                               int* __restrict__ rowStart,
                                               int NC, int N, int E) {
    __shared__ int tmp[512];
    int t = threadIdx.x;
    int v = (t < NC) ? bktTotal[t] : 0;
    tmp[t] = v;
    __syncthreads();
    for (int off = 1; off < 512; off <<= 1) {
        int a = (t >= off) ? tmp[t - off] : 0;
        __syncthreads();
        tmp[t] += a;
        __syncthreads();
    }
    int excl = tmp[t] - v;
    if (t < NC) coarseStart[t] = excl;
    if (t == NC - 1) coarseStart[NC] = excl + v;   // == E
    if (t == 0) rowStart[N] = E;
}

// ---- pass 1: deterministic placement into dense coarse-sorted array ----
// tmp1[pos] = src | (dloc << 17); no global atomics.
__global__ __launch_bounds__(256) void k_part1(const int* __restrict__ src,
                                               const int* __restrict__ dst,
                                               const int* __restrict__ hmat,
                                               const int* __restrict__ coarseStart,
                                               int* __restrict__ tmp1,
                                               int E, int NC) {
    __shared__ int bcnt[MAXC];
    __shared__ int bbase[MAXC];
    int tid = threadIdx.x, blk = blockIdx.x;
    for (int i = tid; i < NC; i += 256) {
        bcnt[i] = 0;
        bbase[i] = coarseStart[i] + hmat[blk * MAXC + i];   // coalesced
    }
    __syncthreads();
    int e0 = blk * EPB, e1 = min(e0 + EPB, E);
    for (int e = e0 + tid; e < e1; e += 256) {
        int s = src[e], d = dst[e];
        int cb = d >> 8;
        int slot = bbase[cb] + atomicAdd(&bcnt[cb], 1);
        tmp1[slot] = s | ((d & 255) << 17);
    }
}

// ---- pass 2 (fused): per-bucket degree->dis/rowStart, then place into CSR ----
// esrc holds BYTE offsets (s*128). Placement is staged in LDS (bucket's esrc
// region [r0,r1) is contiguous) then written coalesced -- avoids the 64B-line
// write amplification k_place's counters exposed (108MB WRITE_SIZE for 6.4MB).
__global__ __launch_bounds__(DPT) void k_degplace(const int* __restrict__ tmp1,
                                                  const int* __restrict__ coarseStart,
                                                  float* __restrict__ dis,
                                                  int* __restrict__ rowStart,
                                                  int* __restrict__ esrc, int N) {
    __shared__ int hist[256];
    __shared__ int scn[256];
    __shared__ int cur[256];
    __shared__ int els[ELS_CAP];
    int tid = threadIdx.x;
    int cb = blockIdx.x;
    int node0 = cb << 8;
    const int r0 = coarseStart[cb], r1 = coarseStart[cb + 1];
    const int cnt = r1 - r0;
    if (tid < 256) hist[tid] = 0;
    __syncthreads();
    for (int i = r0 + tid; i < r1; i += DPT)
        atomicAdd(&hist[((unsigned)tmp1[i]) >> 17], 1);
    __syncthreads();
    int v = 0;
    if (tid < 256) { v = hist[tid]; scn[tid] = v; }
    __syncthreads();
    for (int off = 1; off < 256; off <<= 1) {
        int a = 0;
        if (tid < 256 && tid >= off) a = scn[tid - off];
        __syncthreads();
        if (tid < 256) scn[tid] += a;
        __syncthreads();
    }
    if (tid < 256) {
        int myStart = scn[tid] - v;          // LOCAL (bucket-relative) start
        cur[tid] = myStart;
        int node = node0 + tid;
        if (node < N) {
            dis[node] = rsqrtf((float)v + 1.0f);
            rowStart[node] = r0 + myStart;
        }
    }
    __syncthreads();
    if (cnt <= ELS_CAP) {
        for (int i = r0 + tid; i < r1; i += DPT) {
            int pk = tmp1[i];
            int dl = ((unsigned)pk) >> 17;
            int pos = atomicAdd(&cur[dl], 1);          // local pos
            els[pos] = (pk & 0x1FFFF) << 7;            // byte offset of bf16 row
        }
        __syncthreads();
        for (int i = tid; i < cnt; i += DPT)           // coalesced write-out
            esrc[r0 + i] = els[i];
    } else {   // statistically unreachable fallback: direct scatter
        for (int i = r0 + tid; i < r1; i += DPT) {
            int pk = tmp1[i];
            int dl = ((unsigned)pk) >> 17;
            int pos = atomicAdd(&cur[dl], 1);
            esrc[r0 + pos] = (pk & 0x1FFFF) << 7;
        }
    }
}

// ------- MFMA transform: Hbs[N,64] = bf16( (X[N,K] @ W[K,64]) * dis[row] ) -------
template <int K, typename T>
__global__ __launch_bounds__(256) void k_mmx(const T* __restrict__ X,
                                             const float* __restrict__ W,
                                             const float* __restrict__ dis,
                                             unsigned short* __restrict__ Hbs, int N) {
    constexpr int WP = K + 8;
    __shared__ unsigned short Wt[64 * WP];
    const int tid = threadIdx.x;
    for (int i = tid; i < K * 64; i += 256) {
        int k = i >> 6, n = i & 63;
        Wt[n * WP + k] = f2bf(W[i]);
    }
    __syncthreads();
    const int lane = tid & 63;
    const int m16 = lane & 15;
    const int quad = lane >> 4;
    const int rowBase = blockIdx.x * 64 + (tid >> 6) * 16;
    const int rowc = min(rowBase + m16, N - 1);

    f32x4 acc0 = {0.f, 0.f, 0.f, 0.f};
    f32x4 acc1 = acc0, acc2 = acc0, acc3 = acc0;
    const T* xrow = X + (size_t)rowc * K;
#pragma unroll
    for (int k0 = 0; k0 < K; k0 += 32) {
        bf16x8 af;
        if constexpr (sizeof(T) == 4) {
            const float* xp = (const float*)xrow + k0 + quad * 8;
            float4 xa = *(const float4*)xp;
            float4 xb = *(const float4*)(xp + 4);
            af[0] = (short)f2bf(xa.x); af[1] = (short)f2bf(xa.y);
            af[2] = (short)f2bf(xa.z); af[3] = (short)f2bf(xa.w);
            af[4] = (short)f2bf(xb.x); af[5] = (short)f2bf(xb.y);
            af[6] = (short)f2bf(xb.z); af[7] = (short)f2bf(xb.w);
        } else {
            af = *(const bf16x8*)((const unsigned short*)xrow + k0 + quad * 8);
        }
        const unsigned short* wp = &Wt[m16 * WP + k0 + quad * 8];
        bf16x8 b0 = *(const bf16x8*)(wp);
        bf16x8 b1 = *(const bf16x8*)(wp + 16 * WP);
        bf16x8 b2 = *(const bf16x8*)(wp + 32 * WP);
        bf16x8 b3 = *(const bf16x8*)(wp + 48 * WP);
        acc0 = __builtin_amdgcn_mfma_f32_16x16x32_bf16(af, b0, acc0, 0, 0, 0);
        acc1 = __builtin_amdgcn_mfma_f32_16x16x32_bf16(af, b1, acc1, 0, 0, 0);
        acc2 = __builtin_amdgcn_mfma_f32_16x16x32_bf16(af, b2, acc2, 0, 0, 0);
        acc3 = __builtin_amdgcn_mfma_f32_16x16x32_bf16(af, b3, acc3, 0, 0, 0);
    }
#pragma unroll
    for (int reg = 0; reg < 4; ++reg) {
        int r = rowBase + quad * 4 + reg;
        if (r < N) {
            float dsc = dis[r];
            unsigned short* hp = Hbs + (size_t)r * 64 + m16;
            hp[0]  = f2bf(acc0[reg] * dsc);
            hp[16] = f2bf(acc1[reg] * dsc);
            hp[32] = f2bf(acc2[reg] * dsc);
            hp[48] = f2bf(acc3[reg] * dsc);
        }
    }
}

// ------- gather-aggregate: quarter-wave (16 lanes) per node, dwordx2/lane -----
// Each quarter OWNS its node's edge-offset batches (shfl sources stay inside the
// quarter; quarter-uniform loop bounds -> all 16 lanes of an active quarter are
// active -> bpermute always reads active lanes). Full 16-edge batches issue a
// 16-deep independent-load cascade (128B/lane in flight); tails use 8/4/masked.
// MODE 1: out = relu row, stored bf16 (feeds bf16 mmx)
// MODE 2: relu row, dot with W3, write colS[i] = dot*dis and out[i] = dot*dis^2 + b3

#define BLO(d) __uint_as_float((d) << 16)
#define BHI(d) __uint_as_float((d) & 0xFFFF0000u)
#define ACC2(A, Q) { A.x += BLO((Q).x); A.y += BHI((Q).x);                     \
                     A.z += BLO((Q).y); A.w += BHI((Q).y); }

template <int MODE>
__global__ __launch_bounds__(256) void k_gather64(const unsigned short* __restrict__ Hbs,
                                                  const int* __restrict__ esrc,
                                                  const int* __restrict__ rowStart,
                                                  const float* __restrict__ dis,
                                                  const float* __restrict__ b,
                                                  unsigned short* __restrict__ outB,
                                                  const float* __restrict__ W3,
                                                  const float* __restrict__ b3,
                                                  float* __restrict__ colS,
                                                  float* __restrict__ outF,
                                                  int N) {
    int lane = threadIdx.x & 63;
    int c = lane & 15;          // 8B chunk of the 128B row
    int sub = lane >> 4;        // quarter index == node slot
    int qb = sub << 4;          // quarter's first lane (shfl base)
    int wave = (blockIdx.x * 256 + threadIdx.x) >> 6;
    int g0 = wave * 4;
    if (g0 >= N) return;
    const char* hb = (const char*)Hbs + c * 8;

    int rb = rowStart[min(g0 + lane, N)];      // wave fully active here
    int Rq  = __shfl(rb, sub, 64);             // this quarter's segment [Rq, Rq1)
    int Rq1 = __shfl(rb, sub + 1, 64);
    int n = g0 + sub;                          // this quarter's node
    int nc = min(n, N - 1);

    // self-loop seed: quarter's own row (h[n]*dis[n]); scaled by dis[n] later
    float4 a;
    {
        uint2 sd = *(const uint2*)(hb + ((size_t)nc << 7));
        a.x = BLO(sd.x); a.y = BHI(sd.x); a.z = BLO(sd.y); a.w = BHI(sd.y);
    }

    unsigned eoff = (Rq + c < Rq1) ? (unsigned)esrc[Rq + c] : 0u;
    for (int bb = Rq; bb < Rq1; bb += 16) {
        int cnt = min(16, Rq1 - bb);
        // prefetch next batch's offsets (independent of this batch's work)
        unsigned eoffN = (bb + 16 + c < Rq1) ? (unsigned)esrc[bb + 16 + c] : 0u;

        int j = 0;
        if (cnt == 16) {   // full batch: one 16-deep cascade
            unsigned o0 = __shfl(eoff, qb + 0, 64);
            unsigned o1 = __shfl(eoff, qb + 1, 64);
            unsigned o2 = __shfl(eoff, qb + 2, 64);
            unsigned o3 = __shfl(eoff, qb + 3, 64);
            unsigned o4 = __shfl(eoff, qb + 4, 64);
            unsigned o5 = __shfl(eoff, qb + 5, 64);
            unsigned o6 = __shfl(eoff, qb + 6, 64);
            unsigned o7 = __shfl(eoff, qb + 7, 64);
            unsigned o8 = __shfl(eoff, qb + 8, 64);
            unsigned o9 = __shfl(eoff, qb + 9, 64);
            unsigned oA = __shfl(eoff, qb + 10, 64);
            unsigned oB = __shfl(eoff, qb + 11, 64);
            unsigned oC = __shfl(eoff, qb + 12, 64);
            unsigned oD = __shfl(eoff, qb + 13, 64);
            unsigned oE = __shfl(eoff, qb + 14, 64);
            unsigned oF = __shfl(eoff, qb + 15, 64);
            uint2 q0 = *(const uint2*)(hb + o0);
            uint2 q1 = *(const uint2*)(hb + o1);
            uint2 q2 = *(const uint2*)(hb + o2);
            uint2 q3 = *(const uint2*)(hb + o3);
            uint2 q4 = *(const uint2*)(hb + o4);
            uint2 q5 = *(const uint2*)(hb + o5);
            uint2 q6 = *(const uint2*)(hb + o6);
            uint2 q7 = *(const uint2*)(hb + o7);
            uint2 q8 = *(const uint2*)(hb + o8);
            uint2 q9 = *(const uint2*)(hb + o9);
            uint2 qA = *(const uint2*)(hb + oA);
            uint2 qB = *(const uint2*)(hb + oB);
            uint2 qC = *(const uint2*)(hb + oC);
            uint2 qD = *(const uint2*)(hb + oD);
            uint2 qE = *(const uint2*)(hb + oE);
            uint2 qF = *(const uint2*)(hb + oF);
            ACC2(a, q0) ACC2(a, q1) ACC2(a, q2) ACC2(a, q3)
            ACC2(a, q4) ACC2(a, q5) ACC2(a, q6) ACC2(a, q7)
            ACC2(a, q8) ACC2(a, q9) ACC2(a, qA) ACC2(a, qB)
            ACC2(a, qC) ACC2(a, qD) ACC2(a, qE) ACC2(a, qF)
            j = 16;
        } else {
            for (; j + 8 <= cnt; j += 8) {
                unsigned o0 = __shfl(eoff, qb + j + 0, 64);
                unsigned o1 = __shfl(eoff, qb + j + 1, 64);
                unsigned o2 = __shfl(eoff, qb + j + 2, 64);
                unsigned o3 = __shfl(eoff, qb + j + 3, 64);
                unsigned o4 = __shfl(eoff, qb + j + 4, 64);
                unsigned o5 = __shfl(eoff, qb + j + 5, 64);
                unsigned o6 = __shfl(eoff, qb + j + 6, 64);
                unsigned o7 = __shfl(eoff, qb + j + 7, 64);
                uint2 q0 = *(const uint2*)(hb + o0);
                uint2 q1 = *(const uint2*)(hb + o1);
                uint2 q2 = *(const uint2*)(hb + o2);
                uint2 q3 = *(const uint2*)(hb + o3);
                uint2 q4 = *(const uint2*)(hb + o4);
                uint2 q5 = *(const uint2*)(hb + o5);
                uint2 q6 = *(const uint2*)(hb + o6);
                uint2 q7 = *(const uint2*)(hb + o7);
                ACC2(a, q0) ACC2(a, q1) ACC2(a, q2) ACC2(a, q3)
                ACC2(a, q4) ACC2(a, q5) ACC2(a, q6) ACC2(a, q7)
            }
            if (j + 4 <= cnt) {
                unsigned o0 = __shfl(eoff, qb + j + 0, 64);
                unsigned o1 = __shfl(eoff, qb + j + 1, 64);
                unsigned o2 = __shfl(eoff, qb + j + 2, 64);
                unsigned o3 = __shfl(eoff, qb + j + 3, 64);
                uint2 q0 = *(const uint2*)(hb + o0);
                uint2 q1 = *(const uint2*)(hb + o1);
                uint2 q2 = *(const uint2*)(hb + o2);
                uint2 q3 = *(const uint2*)(hb + o3);
                ACC2(a, q0) ACC2(a, q1) ACC2(a, q2) ACC2(a, q3)
                j += 4;
            }
            if (j < cnt) {   // masked remainder 1..3 (slot 0 always valid)
                bool v1 = j + 1 < cnt, v2 = j + 2 < cnt;
                unsigned o0 = __shfl(eoff, qb + j, 64);
                unsigned o1 = __shfl(eoff, v1 ? qb + j + 1 : qb + j, 64);
                unsigned o2 = __shfl(eoff, v2 ? qb + j + 2 : qb + j, 64);
                uint2 q0 = *(const uint2*)(hb + o0);
                uint2 q1 = *(const uint2*)(hb + o1);
                uint2 q2 = *(const uint2*)(hb + o2);
                if (!v1) { q1.x = 0u; q1.y = 0u; }
                if (!v2) { q2.x = 0u; q2.y = 0u; }
                ACC2(a, q0) ACC2(a, q1) ACC2(a, q2)
            }
        }
        eoff = eoffN;
    }

    // epilogue: each quarter finalizes its own node; no cross-sub reduction
    float ds = dis[nc];
    float4 bl = ((const float4*)b)[c];
    float4 v;
    v.x = fmaxf(a.x * ds + bl.x, 0.f);
    v.y = fmaxf(a.y * ds + bl.y, 0.f);
    v.z = fmaxf(a.z * ds + bl.z, 0.f);
    v.w = fmaxf(a.w * ds + bl.w, 0.f);

    if (MODE == 1) {
        uint2 pv;
        pv.x = (unsigned)f2bf(v.x) | ((unsigned)f2bf(v.y) << 16);
        pv.y = (unsigned)f2bf(v.z) | ((unsigned)f2bf(v.w) << 16);
        if (n < N) ((uint2*)outB)[(size_t)n * 16 + c] = pv;   // 512B/wave coalesced
    } else {
        float4 w3 = ((const float4*)W3)[c];
        float t = v.x * w3.x + v.y * w3.y + v.z * w3.z + v.w * w3.w;
        t += __shfl_xor(t, 1, 64);
        t += __shfl_xor(t, 2, 64);
        t += __shfl_xor(t, 4, 64);
        t += __shfl_xor(t, 8, 64);
        if (c == 0 && n < N) {
            colS[n] = t * ds;
            outF[n] = t * ds * ds + b3[0];
        }
    }
}

// layer-3 aggregation: stage block's colS values in LDS (parallel loads),
// then per-node serial sum out of LDS. out[i] += dis[i] * sum colS[esrc>>7]
__global__ __launch_bounds__(256) void k_gather1(const float* __restrict__ colS,
                                                 const int* __restrict__ esrc,
                                                 const int* __restrict__ rowStart,
                                                 const float* __restrict__ dis,
                                                 float* __restrict__ out, int N) {
    __shared__ float ls[G1CAP];
    int tid = threadIdx.x;
    int n0 = blockIdx.x * 256;
    int nEnd = min(n0 + 256, N);
    int r0 = rowStart[n0];
    int r1 = rowStart[nEnd];
    int cnt = r1 - r0;
    if (cnt <= G1CAP) {
        for (int i = tid; i < cnt; i += 256)
            ls[i] = colS[((unsigned)esrc[r0 + i]) >> 7];
        __syncthreads();
        int n = n0 + tid;
        if (n < N) {
            int a = rowStart[n] - r0, bnd = rowStart[n + 1] - r0;
            float acc = 0.0f;
            for (int e = a; e < bnd; ++e) acc += ls[e];
            out[n] += acc * dis[n];
        }
    } else {   // statistically unreachable fallback
        int n = n0 + tid;
        if (n < N) {
            int a = rowStart[n], bnd = rowStart[n + 1];
            float acc = 0.0f;
            for (int e = a; e < bnd; ++e) acc += colS[((unsigned)esrc[e]) >> 7];
            out[n] += acc * dis[n];
        }
    }
}

extern "C" void kernel_launch(void* const* d_in, const int* in_sizes, int n_in,
                              void* d_out, int out_size, void* d_ws, size_t ws_size,
                              hipStream_t stream) {
    const float* x  = (const float*)d_in[0];
    const int*   ei = (const int*)d_in[1];
    const float* W1 = (const float*)d_in[2];
    const float* b1 = (const float*)d_in[3];
    const float* W2 = (const float*)d_in[4];
    const float* b2 = (const float*)d_in[5];
    const float* W3 = (const float*)d_in[6];
    const float* b3 = (const float*)d_in[7];
    float* out = (float*)d_out;

    const int N = in_sizes[0] / IN_DIM;     // 100000
    const int E = in_sizes[1] / 2;          // 1600000
    const int* src = ei;
    const int* dst = ei + E;
    const int NC = (N + 255) >> 8;          // 391 coarse buckets
    const int NBLK = (E + EPB - 1) / EPB;   // 391 partition blocks

    // ---- workspace layout ----
    char* w = (char*)d_ws;
    auto alloc = [&](size_t bytes) {
        char* p = w;
        w += (bytes + 1023) & ~(size_t)1023;
        return p;
    };
    float*          dis        = (float*)alloc((size_t)N * 4);
    unsigned short* Hbs        = (unsigned short*)alloc((size_t)N * 64 * 2);
    unsigned short* Hb1        = (unsigned short*)alloc((size_t)N * 64 * 2);
    float*          colS       = (float*)alloc((size_t)N * 4);
    int*            rowStart   = (int*)alloc((size_t)(N + 1) * 4);
    int*            bktTotal   = (int*)alloc((size_t)MAXC * 4);
    int*            coarseStart= (int*)alloc((size_t)(MAXC + 1) * 4);
    int*            hmat       = (int*)alloc((size_t)MAXB * MAXC * 4);
    int*            esrc       = (int*)alloc((size_t)E * 4);
    int*            tmp1       = (int*)alloc((size_t)E * 4);

    const int NB_N  = (N + 255) / 256;
    const int NB_MX = (N + 63) / 64;                    // MFMA transform blocks
    const int NB_G4 = ((N + 3) / 4 * 64 + 255) / 256;   // 4 nodes per wave

    // ---- deterministic partition (no global atomics, no memset) ----
    k_hist2<<<NBLK, 256, 0, stream>>>(dst, hmat, E, NC);
    k_bktscan<<<NC, 512, 0, stream>>>(hmat, bktTotal, NBLK, NC);
    k_cscan<<<1, 512, 0, stream>>>(bktTotal, coarseStart, rowStart, NC, N, E);
    k_part1<<<NBLK, 256, 0, stream>>>(src, dst, hmat, coarseStart, tmp1, E, NC);
    k_degplace<<<NC, DPT, 0, stream>>>(tmp1, coarseStart, dis, rowStart, esrc, N);

    // ---- layer 1: mmx fp32->bf16, gather -> bf16 rows ----
    k_mmx<IN_DIM, float><<<NB_MX, 256, 0, stream>>>(x, W1, dis, Hbs, N);
    k_gather64<1><<<NB_G4, 256, 0, stream>>>(Hbs, esrc, rowStart, dis, b1,
                                             Hb1, nullptr, nullptr, nullptr, nullptr, N);

    // ---- layer 2: mmx bf16 input, gather fused with W3 dot ----
    k_mmx<HID, unsigned short><<<NB_MX, 256, 0, stream>>>(Hb1, W2, dis, Hbs, N);
    k_gather64<2><<<NB_G4, 256, 0, stream>>>(Hbs, esrc, rowStart, dis, b2,
                                             nullptr, W3, b3, colS, out, N);

    // ---- layer 3 aggregation ----
    k_gather1<<<NB_N, 256, 0, stream>>>(colS, esrc, rowStart, dis, out, N);
}